// Round 1
// baseline (695.672 us; speedup 1.0000x reference)
//
#include <hip/hip_runtime.h>
#include <hip/hip_bf16.h>

#define EDGES   640000
#define NNODES  50000
#define MDIM    128
#define HDIM    64
#define XSTR    36    // padded LDS stride (floats) for f32 staging kernels

typedef __attribute__((ext_vector_type(8))) short bshort8;  // 8 bf16 = 4 VGPRs
typedef __attribute__((ext_vector_type(4))) float f32x4;    // MFMA acc

__device__ __forceinline__ short f2bf(float f) {
    __hip_bfloat16 h = __float2bfloat16(f);
    return *reinterpret_cast<short*>(&h);
}

// exact-gelu via Abramowitz-Stegun 7.1.26 erf approx (|err| < 1.5e-7)
__device__ __forceinline__ float gelu_fast(float h) {
    const float x  = h * 0.70710678118654752f;
    const float ax = fabsf(x);
    const float t  = __builtin_amdgcn_rcpf(fmaf(0.3275911f, ax, 1.0f));
    float p = fmaf(1.061405429f, t, -1.453152027f);
    p = fmaf(p, t,  1.421413741f);
    p = fmaf(p, t, -0.284496736f);
    p = fmaf(p, t,  0.254829592f);
    p *= t;
    const float e = __expf(-x * x);
    float er = fmaf(-p, e, 1.0f);
    er = (x < 0.0f) ? -er : er;
    return 0.5f * h * (1.0f + er);
}

// ---------------- K0: pack W1 message-half into bf16 MFMA B-fragment layout (bpack),
//                  and W1 feature-half transposed f32 (w1dt) for kg_nodes.
__global__ void k0_prep(const float* __restrict__ w1,
                        short* __restrict__ bpack, float* __restrict__ w1dt) {
    const int i = blockIdx.x * 256 + threadIdx.x;   // 0..16383
    if (i < 8192) {
        const int ii   = i & 7;
        const int lane = (i >> 3) & 63;
        const int jtkc = i >> 9;            // kc*4 + jt
        const int kc = jtkc >> 2, jt = jtkc & 3;
        const int j = jt * 16 + (lane & 15);
        const int k = kc * 32 + (lane >> 4) * 8 + ii;
        bpack[i] = f2bf(w1[j * 256 + k]);
    } else if (i < 16384) {
        const int t = i - 8192;             // w1dt[k][j] = W1[j][128+k]
        const int k = t >> 6, j = t & 63;
        w1dt[t] = w1[j * 256 + 128 + k];
    }
}

// ---------------- KHIST: per-node in-degree (CSR build no longer depends on the MLP)
__global__ void khist(const int* __restrict__ tgt, int* __restrict__ counts) {
    const int e = blockIdx.x * 256 + threadIdx.x;
    if (e < EDGES) atomicAdd(&counts[tgt[e]], 1);
}

// ---------------- KG: g[n][j] = b1[j] + sum_k feats[n][k]*W1d[j][k]  (f32 FMA, lane-per-node)
__global__ __launch_bounds__(256, 4) void kg_nodes(
    const float* __restrict__ feats, const float* __restrict__ w1dt,
    const float* __restrict__ b1, float* __restrict__ g)
{
    __shared__ float xs[4][64 * XSTR];
    const int wv = threadIdx.x >> 6, L = threadIdx.x & 63;
    const long base = ((long)blockIdx.x * 4 + wv) * 64;
    float* xb = xs[wv];
    float h[HDIM];
#pragma unroll
    for (int j = 0; j < HDIM; ++j) h[j] = 0.0f;
    const int gq = L >> 3, sub = L & 7;
    for (int c = 0; c < 4; ++c) {
        const int col0 = c * 32;
#pragma unroll
        for (int r = 0; r < 8; ++r) {
            long row = base + gq + 8 * r;
            if (row > NNODES - 1) row = NNODES - 1;
            float4 v = *(const float4*)(feats + row * MDIM + col0 + sub * 4);
            *(float4*)(xb + (gq + 8 * r) * XSTR + sub * 4) = v;
        }
        __syncthreads();
        for (int k4 = 0; k4 < 8; ++k4) {
            const float4 xv = *(const float4*)(xb + L * XSTR + 4 * k4);
            const float* colw = w1dt + (c * 32 + 4 * k4) * HDIM;
            const float xa[4] = {xv.x, xv.y, xv.z, xv.w};
#pragma unroll
            for (int kk = 0; kk < 4; ++kk) {
                const float xk = xa[kk];
#pragma unroll
                for (int j = 0; j < HDIM; ++j)
                    h[j] = fmaf(colw[kk * HDIM + j], xk, h[j]);
            }
        }
        __syncthreads();
    }
    const long row = base + L;
    if (row < NNODES) {
        float* gp = g + row * HDIM;
#pragma unroll
        for (int j4 = 0; j4 < 16; ++j4) {
            float4 b4 = *(const float4*)(b1 + 4 * j4);
            float4 o;
            o.x = h[4 * j4 + 0] + b4.x; o.y = h[4 * j4 + 1] + b4.y;
            o.z = h[4 * j4 + 2] + b4.z; o.w = h[4 * j4 + 3] + b4.w;
            *(float4*)(gp + 4 * j4) = o;
        }
    }
}

// ---------------- CSR build (unchanged)
__global__ void kscan_local(const int* __restrict__ counts, int* __restrict__ offsets,
                            int* __restrict__ blocksums) {
    __shared__ int s[256];
    const int tid = threadIdx.x;
    const int i = blockIdx.x * 256 + tid;
    int v = (i < NNODES) ? counts[i] : 0;
    s[tid] = v;
    __syncthreads();
    for (int d = 1; d < 256; d <<= 1) {
        int t = (tid >= d) ? s[tid - d] : 0;
        __syncthreads();
        s[tid] += t;
        __syncthreads();
    }
    if (i < NNODES) offsets[i] = s[tid];
    if (tid == 255) blocksums[blockIdx.x] = s[255];
}

__global__ void kscan_blk(int* __restrict__ blocksums, int nblk) {
    __shared__ int s[256];
    const int tid = threadIdx.x;
    int v = (tid < nblk) ? blocksums[tid] : 0;
    s[tid] = v;
    __syncthreads();
    for (int d = 1; d < 256; d <<= 1) {
        int t = (tid >= d) ? s[tid - d] : 0;
        __syncthreads();
        s[tid] += t;
        __syncthreads();
    }
    if (tid < nblk) blocksums[tid] = s[tid] - v;
}

__global__ void kscan_fix(int* __restrict__ offsets, const int* __restrict__ blocksums,
                          const int* __restrict__ counts, int* __restrict__ cursor) {
    const int i = blockIdx.x * 256 + threadIdx.x;
    if (i < NNODES) {
        const int incl = offsets[i] + blocksums[i >> 8];
        offsets[i] = incl;
        cursor[i] = incl - counts[i];
    }
}

__global__ void kscatter(const int* __restrict__ tgt, int* __restrict__ cursor,
                         int* __restrict__ eidx) {
    const int e = blockIdx.x * 256 + threadIdx.x;
    if (e < EDGES) {
        const int pos = atomicAdd(&cursor[tgt[e]], 1);
        eidx[pos] = e;
    }
}

// ---------------- KFUSED: wave-per-node. For each 16-edge tile of the node's CSR list:
//   stage msg rows (f32) to wave-private LDS + cvt to bf16 A-frags in-register,
//   MFMA -> h, +g[node] (uniform row), gelu, dot w2, sigmoid -> w (padded slots w=0),
//   then accumulate acc += w * msg from LDS.  Single msgs read; fused divide+LayerNorm.
//   No __syncthreads: LDS is wave-private, DS ops are in-order within a wave.
__global__ __launch_bounds__(256, 4) void kfused(
    const float* __restrict__ msgs, const int* __restrict__ eidx,
    const int* __restrict__ offsets, const short* __restrict__ bpack,
    const float* __restrict__ g, const float* __restrict__ w2,
    const float* __restrict__ gamma, const float* __restrict__ beta,
    float* __restrict__ out)
{
    __shared__ float lds[4][16][132];   // 33792 B/block, 4 blocks/CU -> 135 KB
    const int wv = threadIdx.x >> 6, L = threadIdx.x & 63;
    const int node = blockIdx.x * 4 + wv;
    if (node >= NNODES) return;
    const int end = offsets[node];
    const int beg = (node == 0) ? 0 : offsets[node - 1];
    const int m = end - beg;

    const int n = L & 15, quad = L >> 4;
    float (*xb)[132] = lds[wv];
    const bshort8* bp = (const bshort8*)bpack;

    // per-wave constants: w2 row and the node's g row (uniform across all edges!)
    float w2v[4], gv[4];
    const float* gp = g + (long)node * HDIM;
#pragma unroll
    for (int jt = 0; jt < 4; ++jt) {
        w2v[jt] = w2[jt * 16 + n];
        gv[jt]  = gp[jt * 16 + n];
    }

    float2 acc = {0.0f, 0.0f};
    float swl = 0.0f;

    for (int t0 = 0; t0 < m; t0 += 16) {
        // edge id of this lane's A-row (all 4 quads read the same addr -> broadcast)
        const int sn = t0 + n;
        const int eid = eidx[beg + ((sn < m) ? sn : 0)];   // clamp pads to slot 0's row (L1-hot)
        const float* rp = msgs + (long)eid * MDIM;

        // load row n, cols {kc*32 + quad*8 .. +8} for kc=0..3  (exactly this lane's A-frag data)
        float4 v[8];
#pragma unroll
        for (int kc = 0; kc < 4; ++kc) {
            v[2 * kc]     = *(const float4*)(rp + kc * 32 + quad * 8);
            v[2 * kc + 1] = *(const float4*)(rp + kc * 32 + quad * 8 + 4);
        }
        // stage f32 to LDS for the accumulation pass
#pragma unroll
        for (int kc = 0; kc < 4; ++kc) {
            *(float4*)(&xb[n][kc * 32 + quad * 8])     = v[2 * kc];
            *(float4*)(&xb[n][kc * 32 + quad * 8 + 4]) = v[2 * kc + 1];
        }

        // MFMA: H[16,64] = bf16(tile) @ W1m^T
        f32x4 hacc[4];
#pragma unroll
        for (int jt = 0; jt < 4; ++jt) hacc[jt] = (f32x4){0.f, 0.f, 0.f, 0.f};
#pragma unroll
        for (int kc = 0; kc < 4; ++kc) {
            const float4 va = v[2 * kc], vb = v[2 * kc + 1];
            bshort8 a;
            a[0] = f2bf(va.x); a[1] = f2bf(va.y); a[2] = f2bf(va.z); a[3] = f2bf(va.w);
            a[4] = f2bf(vb.x); a[5] = f2bf(vb.y); a[6] = f2bf(vb.z); a[7] = f2bf(vb.w);
#pragma unroll
            for (int jt = 0; jt < 4; ++jt)
                hacc[jt] = __builtin_amdgcn_mfma_f32_16x16x32_bf16(a, bp[(kc * 4 + jt) * 64 + L], hacc[jt], 0, 0, 0);
        }

        // epilogue: lane holds h[slot = quad*4+r][j = jt*16+n]
        float wq[4];
#pragma unroll
        for (int r = 0; r < 4; ++r) {
            float raw = 0.0f;
#pragma unroll
            for (int jt = 0; jt < 4; ++jt) {
                const float hj = hacc[jt][r] + gv[jt];
                raw = fmaf(gelu_fast(hj), w2v[jt], raw);
            }
#pragma unroll
            for (int off = 1; off < 16; off <<= 1)
                raw += __shfl_xor(raw, off, 64);
            const int slot = t0 + quad * 4 + r;
            wq[r] = (slot < m) ? __builtin_amdgcn_rcpf(1.0f + __expf(-raw)) : 0.0f;
        }

        // accumulate the 16 edges (wi broadcast from quad i>>2; padded slots have wi = 0)
#pragma unroll
        for (int i = 0; i < 16; ++i) {
            const float wi = __shfl(wq[i & 3], (i >> 2) << 4, 64);
            swl += wi;                                    // every lane sums all wi -> no reduce later
            const float2 mv = *(const float2*)(&xb[i][2 * L]);
            acc.x = fmaf(mv.x, wi, acc.x);
            acc.y = fmaf(mv.y, wi, acc.y);
        }
    }

    // fused divide + LayerNorm
    float s1 = acc.x + acc.y;
    float s2 = acc.x * acc.x + acc.y * acc.y;
#pragma unroll
    for (int off = 32; off; off >>= 1) {
        s1 += __shfl_xor(s1, off, 64);
        s2 += __shfl_xor(s2, off, 64);
    }
    const float inv = 1.0f / (swl + 1e-8f);
    float2 a;
    a.x = acc.x * inv; a.y = acc.y * inv;
    const float mu = s1 * inv * (1.0f / MDIM);
    const float var = s2 * inv * inv * (1.0f / MDIM) - mu * mu;
    const float rs = rsqrtf(var + 1e-5f);
    const float2 gm = *(const float2*)(gamma + 2 * L);
    const float2 bt = *(const float2*)(beta + 2 * L);
    float2 o;
    o.x = (a.x - mu) * rs * gm.x + bt.x;
    o.y = (a.y - mu) * rs * gm.y + bt.y;
    *(float2*)(out + (long)node * MDIM + 2 * L) = o;
}

extern "C" void kernel_launch(void* const* d_in, const int* in_sizes, int n_in,
                              void* d_out, int out_size, void* d_ws, size_t ws_size,
                              hipStream_t stream) {
    const float* msgs  = (const float*)d_in[0];
    const int*   tgt   = (const int*)d_in[1];
    const float* feats = (const float*)d_in[2];
    const float* W1    = (const float*)d_in[4];
    const float* b1    = (const float*)d_in[5];
    const float* W2    = (const float*)d_in[6];
    const float* gamma = (const float*)d_in[7];
    const float* beta  = (const float*)d_in[8];
    float* out = (float*)d_out;

    char* ws = (char*)d_ws;
    short* bpack   = (short*)(ws + 0);                 //  16 KB
    float* w1dt    = (float*)(ws + (32 << 10));        //  32 KB
    int*   counts  = (int*)  (ws + (64 << 10));        // 200 KB
    int*   offsets = (int*)  (ws + (320 << 10));       // 200 KB
    int*   cursor  = (int*)  (ws + (576 << 10));       // 200 KB
    int*   bsums   = (int*)  (ws + (832 << 10));       //   1 KB
    int*   eidx    = (int*)  (ws + (4 << 20));         // 2.56 MB
    float* g       = (float*)(ws + (8 << 20));         // 12.8 MB

    hipMemsetAsync(counts, 0, NNODES * sizeof(int), stream);

    k0_prep<<<64, 256, 0, stream>>>(W1, bpack, w1dt);
    khist<<<(EDGES + 255) / 256, 256, 0, stream>>>(tgt, counts);
    kg_nodes<<<(NNODES + 255) / 256, 256, 0, stream>>>(feats, w1dt, b1, g);
    const int nblk = (NNODES + 255) / 256;
    kscan_local<<<nblk, 256, 0, stream>>>(counts, offsets, bsums);
    kscan_blk<<<1, 256, 0, stream>>>(bsums, nblk);
    kscan_fix<<<nblk, 256, 0, stream>>>(offsets, bsums, counts, cursor);
    kscatter<<<(EDGES + 255) / 256, 256, 0, stream>>>(tgt, cursor, eidx);
    kfused<<<(NNODES + 3) / 4, 256, 0, stream>>>(msgs, eidx, offsets, bpack, g, W2, gamma, beta, out);
}